// Round 4
// baseline (239.337 us; speedup 1.0000x reference)
//
#include <hip/hip_runtime.h>
#include <hip/hip_bf16.h>

// EMAQuantizer: z[32][512][32][32] fp32, embedding[1024][512] fp32.
// d_out fp32 concat: quantized [32][512][32][32] then indices [32][1024].
#define CDIM 512
#define KDIM 1024
#define HW   1024
#define NPOS 32768
#define BM   128            // positions per block
#define BN   128            // codes per block
#define BK   64             // channels per K-step
#define NKS  (CDIM / BK)    // 8 K-steps
#define NNB  (KDIM / BN)    // 8 code-blocks
#define TILE_USHORT (8 * 128 * 8)   // one 16KB tile image in ushorts

typedef float  f32x16 __attribute__((ext_vector_type(16)));
typedef float  f4     __attribute__((ext_vector_type(4)));
typedef short  bf16x8 __attribute__((ext_vector_type(8)));
typedef unsigned int u32x4 __attribute__((ext_vector_type(4)));

static __device__ __forceinline__ unsigned short f2bf(float f) {
    __hip_bfloat16 h = __float2bfloat16(f);           // RNE
    union { __hip_bfloat16 h; unsigned short u; } cv; cv.h = h; return cv.u;
}
static __device__ __forceinline__ float bf2f(unsigned short u) {
    union { unsigned short u; __hip_bfloat16 h; } cv; cv.u = u; return __bfloat162float(cv.h);
}

// ---------------------------------------------------------------------------
// prep_e: embedding -> Bt_hi/Bt_lo in GEMM tile-image layout + enorm.
// Tile image for (nb, ks): [slot 0..7][row 0..127][8 bf16] (16 KB).
// grid: KDIM blocks x 64 threads (1 wave).  (unchanged from round 3)
// ---------------------------------------------------------------------------
__global__ __launch_bounds__(64) void prep_e(const float* __restrict__ e,
                                             unsigned short* __restrict__ Bt_hi,
                                             unsigned short* __restrict__ Bt_lo,
                                             float* __restrict__ enorm) {
    const int k  = blockIdx.x;
    const int t  = threadIdx.x;
    const int nb = k >> 7, row = k & 127;
    const int ks = t >> 3, slot = t & 7;

    const f4* src = (const f4*)(e + (size_t)k * CDIM + ks * 64 + slot * 8);
    const f4 a = src[0], b = src[1];
    float v[8] = {a.x, a.y, a.z, a.w, b.x, b.y, b.z, b.w};

    unsigned int hw_[4], lw_[4];
    float ss = 0.0f;
    #pragma unroll
    for (int d = 0; d < 4; ++d) {
        const float v0 = v[2 * d], v1 = v[2 * d + 1];
        const unsigned short h0 = f2bf(v0), h1 = f2bf(v1);
        hw_[d] = (unsigned int)h0 | ((unsigned int)h1 << 16);
        lw_[d] = (unsigned int)f2bf(v0 - bf2f(h0)) |
                 ((unsigned int)f2bf(v1 - bf2f(h1)) << 16);
        ss += v0 * v0 + v1 * v1;
    }
    const size_t off = ((((size_t)nb * 8 + ks) * 8 + slot) * 128 + row) * 8;
    *(u32x4*)(Bt_hi + off) = u32x4{hw_[0], hw_[1], hw_[2], hw_[3]};
    *(u32x4*)(Bt_lo + off) = u32x4{lw_[0], lw_[1], lw_[2], lw_[3]};

    #pragma unroll
    for (int o = 32; o > 0; o >>= 1) ss += __shfl_down(ss, o, 64);
    if (t == 0) enorm[k] = ss;
}

// ---------------------------------------------------------------------------
// vq_gemm: 128 pos x 128 codes per block, 3-pass split-bf16 MFMA.
// Round-4 change: software-pipelined — global loads for ks+1 issue BEFORE
// MFMA(ks), so the __syncthreads vmcnt(0) drain at the next iteration lands
// after ~384 cy of MFMA instead of immediately after issue.
// grid: (NPOS/BM)*NNB = 2048 blocks x 256 threads.
// ---------------------------------------------------------------------------
__global__ __launch_bounds__(256) void vq_gemm(const float* __restrict__ z,
                                               const unsigned short* __restrict__ Bt_hi,
                                               const unsigned short* __restrict__ Bt_lo,
                                               const float* __restrict__ enorm,
                                               float2* __restrict__ part) {
    __shared__ unsigned short Ah[8][128][8], Al[8][128][8];
    __shared__ unsigned short Bh[8][128][8], Bl[8][128][8];
    __shared__ float lval[2][128];
    __shared__ int   lidx[2][128];

    // XCD-chunked order: the 8 nb-blocks sharing one z-panel land on one XCD.
    const int bid = blockIdx.x;
    const int x = bid & 7, jj = bid >> 3;
    const int m  = x * 32 + (jj >> 3);
    const int nb = jj & 7;

    const int n0  = m * BM;
    const int b   = n0 >> 10;
    const int hw0 = n0 & 1023;

    const int t   = threadIdx.x;
    const int wid = t >> 6, l = t & 63;
    const int wr  = wid >> 1, wc = wid & 1;   // code-half, pos-half

    f32x16 acc[2][2];
    #pragma unroll
    for (int i = 0; i < 2; ++i)
        #pragma unroll
        for (int j = 0; j < 2; ++j) acc[i][j] = (f32x16)0.0f;

    const float* zbase = z + (size_t)b * CDIM * HW + hw0;
    const int sp = t & 127;      // staging pos
    const int sh = t >> 7;       // staging c-half (32 channels)

    // staging registers (single buffer: ds_write reads them before reload)
    float v[32];
    u32x4 bhv[4], blv[4];

    // ---- prologue: issue loads for ks = 0 --------------------------------
    {
        const float* zc = zbase + (size_t)(sh * 32) * HW + sp;
        #pragma unroll
        for (int i = 0; i < 32; ++i) v[i] = zc[(size_t)i * HW];
        const u32x4* bsh = (const u32x4*)(Bt_hi + (size_t)nb * 8 * TILE_USHORT);
        const u32x4* bsl = (const u32x4*)(Bt_lo + (size_t)nb * 8 * TILE_USHORT);
        #pragma unroll
        for (int q = 0; q < 4; ++q) { bhv[q] = bsh[q * 256 + t]; blv[q] = bsl[q * 256 + t]; }
    }

    #pragma unroll
    for (int ks = 0; ks < NKS; ++ks) {
        __syncthreads();   // previous MFMA done reading LDS

        // ---- convert + write A (slot-major) ------------------------------
        #pragma unroll
        for (int o = 0; o < 4; ++o) {
            unsigned int hw_[4], lw_[4];
            #pragma unroll
            for (int d = 0; d < 4; ++d) {
                const float a0 = v[o * 8 + 2 * d], a1 = v[o * 8 + 2 * d + 1];
                const unsigned short h0 = f2bf(a0), h1 = f2bf(a1);
                hw_[d] = (unsigned int)h0 | ((unsigned int)h1 << 16);
                lw_[d] = (unsigned int)f2bf(a0 - bf2f(h0)) |
                         ((unsigned int)f2bf(a1 - bf2f(h1)) << 16);
            }
            *(u32x4*)&Ah[sh * 4 + o][sp][0] = u32x4{hw_[0], hw_[1], hw_[2], hw_[3]};
            *(u32x4*)&Al[sh * 4 + o][sp][0] = u32x4{lw_[0], lw_[1], lw_[2], lw_[3]};
        }
        // ---- write B (linear) --------------------------------------------
        unsigned short* bhp = &Bh[0][0][0];
        unsigned short* blp = &Bl[0][0][0];
        #pragma unroll
        for (int q = 0; q < 4; ++q) {
            *(u32x4*)(bhp + (size_t)(q * 256 + t) * 8) = bhv[q];
            *(u32x4*)(blp + (size_t)(q * 256 + t) * 8) = blv[q];
        }
        __syncthreads();

        // ---- issue loads for ks+1 (covered by MFMA below) ----------------
        if (ks + 1 < NKS) {
            const float* zc = zbase + (size_t)((ks + 1) * 64 + sh * 32) * HW + sp;
            #pragma unroll
            for (int i = 0; i < 32; ++i) v[i] = zc[(size_t)i * HW];
            const u32x4* bsh = (const u32x4*)(Bt_hi + ((size_t)nb * 8 + ks + 1) * TILE_USHORT);
            const u32x4* bsl = (const u32x4*)(Bt_lo + ((size_t)nb * 8 + ks + 1) * TILE_USHORT);
            #pragma unroll
            for (int q = 0; q < 4; ++q) { bhv[q] = bsh[q * 256 + t]; blv[q] = bsl[q * 256 + t]; }
        }

        // ---- compute: 4 k-subs x (2x2 frags x 3 passes) ------------------
        #pragma unroll
        for (int ksub = 0; ksub < 4; ++ksub) {
            const int so = 2 * ksub + (l >> 5);
            const int cr = wr * 64 + (l & 31);
            const int pr = wc * 64 + (l & 31);
            const bf16x8 ch0 = *(const bf16x8*)&Bh[so][cr][0];
            const bf16x8 ch1 = *(const bf16x8*)&Bh[so][cr + 32][0];
            const bf16x8 cl0 = *(const bf16x8*)&Bl[so][cr][0];
            const bf16x8 cl1 = *(const bf16x8*)&Bl[so][cr + 32][0];
            const bf16x8 ph0 = *(const bf16x8*)&Ah[so][pr][0];
            const bf16x8 ph1 = *(const bf16x8*)&Ah[so][pr + 32][0];
            const bf16x8 pl0 = *(const bf16x8*)&Al[so][pr][0];
            const bf16x8 pl1 = *(const bf16x8*)&Al[so][pr + 32][0];
            acc[0][0] = __builtin_amdgcn_mfma_f32_32x32x16_bf16(ch0, ph0, acc[0][0], 0, 0, 0);
            acc[0][1] = __builtin_amdgcn_mfma_f32_32x32x16_bf16(ch0, ph1, acc[0][1], 0, 0, 0);
            acc[1][0] = __builtin_amdgcn_mfma_f32_32x32x16_bf16(ch1, ph0, acc[1][0], 0, 0, 0);
            acc[1][1] = __builtin_amdgcn_mfma_f32_32x32x16_bf16(ch1, ph1, acc[1][1], 0, 0, 0);
            acc[0][0] = __builtin_amdgcn_mfma_f32_32x32x16_bf16(ch0, pl0, acc[0][0], 0, 0, 0);
            acc[0][1] = __builtin_amdgcn_mfma_f32_32x32x16_bf16(ch0, pl1, acc[0][1], 0, 0, 0);
            acc[1][0] = __builtin_amdgcn_mfma_f32_32x32x16_bf16(ch1, pl0, acc[1][0], 0, 0, 0);
            acc[1][1] = __builtin_amdgcn_mfma_f32_32x32x16_bf16(ch1, pl1, acc[1][1], 0, 0, 0);
            acc[0][0] = __builtin_amdgcn_mfma_f32_32x32x16_bf16(cl0, ph0, acc[0][0], 0, 0, 0);
            acc[0][1] = __builtin_amdgcn_mfma_f32_32x32x16_bf16(cl0, ph1, acc[0][1], 0, 0, 0);
            acc[1][0] = __builtin_amdgcn_mfma_f32_32x32x16_bf16(cl1, ph0, acc[1][0], 0, 0, 0);
            acc[1][1] = __builtin_amdgcn_mfma_f32_32x32x16_bf16(cl1, ph1, acc[1][1], 0, 0, 0);
        }
    }

    // ---- argmin epilogue: dist = enorm[code] - 2*dot ---------------------
    // C/D layout (m74/m101): col = lane&31 (pos), row = (reg&3)+8*(reg>>2)+4*(lane>>5).
    const float* en = enorm + nb * 128 + wr * 64;
    #pragma unroll
    for (int pj = 0; pj < 2; ++pj) {
        float bv = 1e30f; int bi = 1 << 20;
        #pragma unroll
        for (int ci = 0; ci < 2; ++ci) {
            #pragma unroll
            for (int r = 0; r < 16; ++r) {
                const int code = ci * 32 + (r & 3) + 8 * (r >> 2) + 4 * (l >> 5);
                const float val = en[code] - 2.0f * acc[ci][pj][r];
                if (val < bv || (val == bv && code < bi)) { bv = val; bi = code; }
            }
        }
        const float ov = __shfl_xor(bv, 32, 64);
        const int   oi = __shfl_xor(bi, 32, 64);
        if (ov < bv || (ov == bv && oi < bi)) { bv = ov; bi = oi; }
        if (l < 32) { lval[wr][wc * 64 + pj * 32 + l] = bv; lidx[wr][wc * 64 + pj * 32 + l] = bi; }
    }
    __syncthreads();

    if (t < 128) {
        const float v0 = lval[0][t]; const int i0 = lidx[0][t];
        const float v1 = lval[1][t]; const int i1 = lidx[1][t] + 64;
        float bv = v0; int bi = i0;
        if (v1 < bv || (v1 == bv && i1 < bi)) { bv = v1; bi = i1; }
        part[(size_t)(n0 + t) * 8 + nb] = make_float2(bv, (float)(nb * 128 + bi));
    }
}

// ---------------------------------------------------------------------------
// vq_reduce: combine 8 partials per position; write indices; gather rows and
// write quantized as f4 (4 positions per thread, 4x4 register transpose).
// grid: NPOS/128 = 256 blocks x 256 threads.
// ---------------------------------------------------------------------------
__global__ __launch_bounds__(256) void vq_reduce(const float2* __restrict__ part,
                                                 const float* __restrict__ e,
                                                 float* __restrict__ out_q,
                                                 float* __restrict__ out_i) {
    __shared__ int bidx[128];
    const int t  = threadIdx.x;
    const int p0 = blockIdx.x * 128;

    if (t < 128) {
        const int n = p0 + t;
        const float2* pr = part + (size_t)n * 8;
        float bv = pr[0].x; int bi = (int)pr[0].y;
        #pragma unroll
        for (int nb = 1; nb < 8; ++nb) {
            const float2 c = pr[nb];
            const int ci = (int)c.y;
            if (c.x < bv || (c.x == bv && ci < bi)) { bv = c.x; bi = ci; }
        }
        bidx[t] = bi;
        out_i[n] = (float)bi;
    }
    __syncthreads();

    // thread: 4 consecutive positions (pq) x 64 channels (cs)
    const int pq = t & 31;               // position quad within block
    const int cs = t >> 5;               // channel set (8 x 64)
    const int n  = p0 + pq * 4;
    const int b  = n >> 10, hwp = n & 1023;

    const int r0 = bidx[pq * 4 + 0], r1 = bidx[pq * 4 + 1];
    const int r2 = bidx[pq * 4 + 2], r3 = bidx[pq * 4 + 3];
    const f4* e0 = (const f4*)(e + (size_t)r0 * CDIM) + cs * 16;
    const f4* e1 = (const f4*)(e + (size_t)r1 * CDIM) + cs * 16;
    const f4* e2 = (const f4*)(e + (size_t)r2 * CDIM) + cs * 16;
    const f4* e3 = (const f4*)(e + (size_t)r3 * CDIM) + cs * 16;
    float* oq = out_q + (size_t)b * CDIM * HW + hwp;

    #pragma unroll 4
    for (int q = 0; q < 16; ++q) {
        const f4 a = e0[q], bb = e1[q], c = e2[q], d = e3[q];
        const int cbase = cs * 64 + q * 4;
        *(f4*)(oq + (size_t)(cbase + 0) * HW) = f4{a.x, bb.x, c.x, d.x};
        *(f4*)(oq + (size_t)(cbase + 1) * HW) = f4{a.y, bb.y, c.y, d.y};
        *(f4*)(oq + (size_t)(cbase + 2) * HW) = f4{a.z, bb.z, c.z, d.z};
        *(f4*)(oq + (size_t)(cbase + 3) * HW) = f4{a.w, bb.w, c.w, d.w};
    }
}

// ---------------------------------------------------------------------------
extern "C" void kernel_launch(void* const* d_in, const int* in_sizes, int n_in,
                              void* d_out, int out_size, void* d_ws, size_t ws_size,
                              hipStream_t stream) {
    const float* z = (const float*)d_in[0];
    const float* e = (const float*)d_in[1];

    float* out_q = (float*)d_out;
    float* out_i = out_q + (out_size - NPOS);

    // ws layout (≈4.2 MB): Bt_hi 1MB | Bt_lo 1MB | enorm 4KB | part 2MB
    unsigned short* Bt_hi = (unsigned short*)d_ws;
    unsigned short* Bt_lo = Bt_hi + (size_t)KDIM * CDIM;
    float*  enorm = (float*)(Bt_lo + (size_t)KDIM * CDIM);
    float2* part  = (float2*)((char*)d_ws + 2 * 1048576 + 4096);

    prep_e<<<KDIM, 64, 0, stream>>>(e, Bt_hi, Bt_lo, enorm);
    vq_gemm<<<(NPOS / BM) * NNB, 256, 0, stream>>>(z, Bt_hi, Bt_lo, enorm, part);
    vq_reduce<<<NPOS / 128, 256, 0, stream>>>(part, e, out_q, out_i);
}

// Round 6
// 235.327 us; speedup vs baseline: 1.0170x; 1.0170x over previous
//
#include <hip/hip_runtime.h>
#include <hip/hip_bf16.h>

// EMAQuantizer: z[32][512][32][32] fp32, embedding[1024][512] fp32.
// d_out fp32 concat: quantized [32][512][32][32] then indices [32][1024].
//
// Pipeline: prep_e (embedding -> hi/lo bf16 tile images in ws)
//           prep_z (z -> hi/lo bf16 tile images in d_out-as-scratch)
//           vq_gemm (global_load_lds DMA staging, 3-pass split-bf16 MFMA)
//           vq_reduce (combine 8 partials, gather, overwrite d_out)
#define CDIM 512
#define KDIM 1024
#define HW   1024
#define NPOS 32768
#define BM   128
#define BN   128
#define BK   32
#define NKS  16             // CDIM/BK
#define NNB  8              // KDIM/BN
#define PAY  8192           // ushorts per (tile,ks) payload: hi 4096 | lo 4096 (16KB)

typedef float  f32x16 __attribute__((ext_vector_type(16)));
typedef float  f4     __attribute__((ext_vector_type(4)));
typedef short  bf16x8 __attribute__((ext_vector_type(8)));
typedef unsigned int u32x4 __attribute__((ext_vector_type(4)));

static __device__ __forceinline__ unsigned short f2bf(float f) {
    __hip_bfloat16 h = __float2bfloat16(f);           // RNE
    union { __hip_bfloat16 h; unsigned short u; } cv; cv.h = h; return cv.u;
}
static __device__ __forceinline__ float bf2f(unsigned short u) {
    union { unsigned short u; __hip_bfloat16 h; } cv; cv.u = u; return __bfloat162float(cv.h);
}

// global (AS1) -> LDS (AS3) 16-byte DMA; dest = wave-uniform base + lane*16.
static __device__ __forceinline__ void gld16(const unsigned short* g, unsigned short* l) {
    __builtin_amdgcn_global_load_lds(
        (const __attribute__((address_space(1))) void*)g,
        (__attribute__((address_space(3))) void*)l,
        16, 0, 0);
}

// ---------------------------------------------------------------------------
// prep_e: embedding row k -> Bt payload images + enorm.
// Bt layout (ushort): [(nb*16+ks)] * PAY + h*4096 + slot*1024 + row*8
//   (h=0 hi, h=1 lo; slot = (c>>3)&3 within 32-ch step ks = c>>5; row = k&127)
// grid: KDIM x 64.
// ---------------------------------------------------------------------------
__global__ __launch_bounds__(64) void prep_e(const float* __restrict__ e,
                                             unsigned short* __restrict__ Bt,
                                             float* __restrict__ enorm) {
    const int k  = blockIdx.x;
    const int t  = threadIdx.x;
    const int nb = k >> 7, row = k & 127;
    const int ks = t >> 2, slot = t & 3;

    const f4* src = (const f4*)(e + (size_t)k * CDIM + t * 8);
    const f4 a = src[0], b = src[1];
    const float v[8] = {a.x, a.y, a.z, a.w, b.x, b.y, b.z, b.w};

    unsigned int hw_[4], lw_[4];
    float ss = 0.0f;
    #pragma unroll
    for (int d = 0; d < 4; ++d) {
        const float v0 = v[2 * d], v1 = v[2 * d + 1];
        const unsigned short h0 = f2bf(v0), h1 = f2bf(v1);
        hw_[d] = (unsigned int)h0 | ((unsigned int)h1 << 16);
        lw_[d] = (unsigned int)f2bf(v0 - bf2f(h0)) |
                 ((unsigned int)f2bf(v1 - bf2f(h1)) << 16);
        ss += v0 * v0 + v1 * v1;
    }
    const size_t base = (size_t)(nb * 16 + ks) * PAY + slot * 1024 + row * 8;
    *(u32x4*)(Bt + base)        = u32x4{hw_[0], hw_[1], hw_[2], hw_[3]};
    *(u32x4*)(Bt + base + 4096) = u32x4{lw_[0], lw_[1], lw_[2], lw_[3]};

    #pragma unroll
    for (int o = 32; o > 0; o >>= 1) ss += __shfl_down(ss, o, 64);
    if (t == 0) enorm[k] = ss;
}

// ---------------------------------------------------------------------------
// prep_z: z -> Az payload images (in d_out scratch). One m-tile (128 pos,
// all 512 ch) per block. Az layout mirrors Bt with pos instead of row:
//   [(m*16+ks)] * PAY + h*4096 + slot*1024 + pos*8
// grid: 256 x 256.
// ---------------------------------------------------------------------------
__global__ __launch_bounds__(256) void prep_z(const float* __restrict__ z,
                                              unsigned short* __restrict__ Az) {
    const int m  = blockIdx.x;
    const int t  = threadIdx.x;
    const int b  = m >> 3;
    const int hw0 = (m & 7) * 128;
    const int sp = t & 127;      // position
    const int sh = t >> 7;       // channel half (32 of each 64)

    const float* zbase = z + (size_t)b * CDIM * HW + hw0 + sp;

    #pragma unroll
    for (int it = 0; it < 8; ++it) {
        const int cbase = it * 64 + sh * 32;
        float v[32];
        #pragma unroll
        for (int i = 0; i < 32; ++i) v[i] = zbase[(size_t)(cbase + i) * HW];

        const int ks = it * 2 + sh;
        const size_t tbase = (size_t)(m * 16 + ks) * PAY + sp * 8;
        #pragma unroll
        for (int slot = 0; slot < 4; ++slot) {
            unsigned int hw_[4], lw_[4];
            #pragma unroll
            for (int d = 0; d < 4; ++d) {
                const float a0 = v[slot * 8 + 2 * d], a1 = v[slot * 8 + 2 * d + 1];
                const unsigned short h0 = f2bf(a0), h1 = f2bf(a1);
                hw_[d] = (unsigned int)h0 | ((unsigned int)h1 << 16);
                lw_[d] = (unsigned int)f2bf(a0 - bf2f(h0)) |
                         ((unsigned int)f2bf(a1 - bf2f(h1)) << 16);
            }
            *(u32x4*)(Az + tbase + slot * 1024)        = u32x4{hw_[0], hw_[1], hw_[2], hw_[3]};
            *(u32x4*)(Az + tbase + slot * 1024 + 4096) = u32x4{lw_[0], lw_[1], lw_[2], lw_[3]};
        }
    }
}

// ---------------------------------------------------------------------------
// vq_gemm: 128 pos x 128 codes, 3-pass split-bf16 MFMA.
// Staging = global_load_lds DMA, double-buffered, ONE barrier per K-step:
//   STAGE(next) -> MFMA(cur) -> __syncthreads (drains vmcnt after ~192cy MFMA)
// LDS buffer (16384 ushorts): A hi 0 | A lo 4096 | B hi 8192 | B lo 12288.
// grid: 2048 x 256.
// ---------------------------------------------------------------------------
__global__ __launch_bounds__(256) void vq_gemm(const unsigned short* __restrict__ Az,
                                               const unsigned short* __restrict__ Bt,
                                               const float* __restrict__ enorm,
                                               float2* __restrict__ part) {
    __shared__ unsigned short lds[2][16384];
    __shared__ float lval[2][128];
    __shared__ int   lidx[2][128];

    // XCD-chunked order: the 8 nb-blocks sharing one z-panel land on one XCD.
    const int bid = blockIdx.x;
    const int x = bid & 7, jj = bid >> 3;
    const int m  = x * 32 + (jj >> 3);
    const int nb = jj & 7;
    const int n0 = m * BM;

    const int t   = threadIdx.x;
    const int wid = t >> 6, l = t & 63;
    const int wr  = wid >> 1, wc = wid & 1;   // code-half, pos-half

    const unsigned short* asrc = Az + (size_t)m  * NKS * PAY;
    const unsigned short* bsrc = Bt + (size_t)nb * NKS * PAY;

    f32x16 acc[2][2];
    #pragma unroll
    for (int i = 0; i < 2; ++i)
        #pragma unroll
        for (int j = 0; j < 2; ++j) acc[i][j] = (f32x16)0.0f;

    // ---- prologue: stage ks=0 into buf 0 ---------------------------------
    #pragma unroll
    for (int i = 0; i < 4; ++i) {
        gld16(asrc + (size_t)(i * 256 + t) * 8, &lds[0][(i * 256 + t) * 8]);
        gld16(bsrc + (size_t)(i * 256 + t) * 8, &lds[0][8192 + (i * 256 + t) * 8]);
    }
    __syncthreads();

    const int pr = wc * 64 + (l & 31);
    const int cr = wr * 64 + (l & 31);
    const int lsel = l >> 5;

    #pragma unroll
    for (int ks = 0; ks < NKS; ++ks) {
        const int cb = ks & 1;
        // ---- stage next K-step into the other buffer ---------------------
        if (ks + 1 < NKS) {
            const unsigned short* an = asrc + (size_t)(ks + 1) * PAY;
            const unsigned short* bn = bsrc + (size_t)(ks + 1) * PAY;
            #pragma unroll
            for (int i = 0; i < 4; ++i) {
                gld16(an + (size_t)(i * 256 + t) * 8, &lds[cb ^ 1][(i * 256 + t) * 8]);
                gld16(bn + (size_t)(i * 256 + t) * 8, &lds[cb ^ 1][8192 + (i * 256 + t) * 8]);
            }
        }
        // ---- compute current buffer --------------------------------------
        __builtin_amdgcn_s_setprio(1);
        #pragma unroll
        for (int ksub = 0; ksub < 2; ++ksub) {
            const int so = ksub * 2 + lsel;
            const bf16x8 ch0 = *(const bf16x8*)&lds[cb][ 8192 + (so * 128 + cr) * 8];
            const bf16x8 ch1 = *(const bf16x8*)&lds[cb][ 8192 + (so * 128 + cr + 32) * 8];
            const bf16x8 cl0 = *(const bf16x8*)&lds[cb][12288 + (so * 128 + cr) * 8];
            const bf16x8 cl1 = *(const bf16x8*)&lds[cb][12288 + (so * 128 + cr + 32) * 8];
            const bf16x8 ph0 = *(const bf16x8*)&lds[cb][        (so * 128 + pr) * 8];
            const bf16x8 ph1 = *(const bf16x8*)&lds[cb][        (so * 128 + pr + 32) * 8];
            const bf16x8 pl0 = *(const bf16x8*)&lds[cb][ 4096 + (so * 128 + pr) * 8];
            const bf16x8 pl1 = *(const bf16x8*)&lds[cb][ 4096 + (so * 128 + pr + 32) * 8];
            acc[0][0] = __builtin_amdgcn_mfma_f32_32x32x16_bf16(ch0, ph0, acc[0][0], 0, 0, 0);
            acc[0][1] = __builtin_amdgcn_mfma_f32_32x32x16_bf16(ch0, ph1, acc[0][1], 0, 0, 0);
            acc[1][0] = __builtin_amdgcn_mfma_f32_32x32x16_bf16(ch1, ph0, acc[1][0], 0, 0, 0);
            acc[1][1] = __builtin_amdgcn_mfma_f32_32x32x16_bf16(ch1, ph1, acc[1][1], 0, 0, 0);
            acc[0][0] = __builtin_amdgcn_mfma_f32_32x32x16_bf16(ch0, pl0, acc[0][0], 0, 0, 0);
            acc[0][1] = __builtin_amdgcn_mfma_f32_32x32x16_bf16(ch0, pl1, acc[0][1], 0, 0, 0);
            acc[1][0] = __builtin_amdgcn_mfma_f32_32x32x16_bf16(ch1, pl0, acc[1][0], 0, 0, 0);
            acc[1][1] = __builtin_amdgcn_mfma_f32_32x32x16_bf16(ch1, pl1, acc[1][1], 0, 0, 0);
            acc[0][0] = __builtin_amdgcn_mfma_f32_32x32x16_bf16(cl0, ph0, acc[0][0], 0, 0, 0);
            acc[0][1] = __builtin_amdgcn_mfma_f32_32x32x16_bf16(cl0, ph1, acc[0][1], 0, 0, 0);
            acc[1][0] = __builtin_amdgcn_mfma_f32_32x32x16_bf16(cl1, ph0, acc[1][0], 0, 0, 0);
            acc[1][1] = __builtin_amdgcn_mfma_f32_32x32x16_bf16(cl1, ph1, acc[1][1], 0, 0, 0);
        }
        __builtin_amdgcn_s_setprio(0);
        // one barrier per K-step: drains stage (vmcnt) after MFMA covered it,
        // and guarantees all waves finished reading lds[cb].
        __syncthreads();
    }

    // ---- argmin epilogue: dist = enorm[code] - 2*dot ---------------------
    // C/D layout (m74/m101): col = lane&31 (pos), row = (reg&3)+8*(reg>>2)+4*(lane>>5).
    const float* en = enorm + nb * 128 + wr * 64;
    #pragma unroll
    for (int pj = 0; pj < 2; ++pj) {
        float bv = 1e30f; int bi = 1 << 20;
        #pragma unroll
        for (int ci = 0; ci < 2; ++ci) {
            #pragma unroll
            for (int r = 0; r < 16; ++r) {
                const int code = ci * 32 + (r & 3) + 8 * (r >> 2) + 4 * lsel;
                const float val = en[code] - 2.0f * acc[ci][pj][r];
                if (val < bv || (val == bv && code < bi)) { bv = val; bi = code; }
            }
        }
        const float ov = __shfl_xor(bv, 32, 64);
        const int   oi = __shfl_xor(bi, 32, 64);
        if (ov < bv || (ov == bv && oi < bi)) { bv = ov; bi = oi; }
        if (l < 32) { lval[wr][wc * 64 + pj * 32 + l] = bv; lidx[wr][wc * 64 + pj * 32 + l] = bi; }
    }
    __syncthreads();

    if (t < 128) {
        const float v0 = lval[0][t]; const int i0 = lidx[0][t];
        const float v1 = lval[1][t]; const int i1 = lidx[1][t] + 64;
        float bv = v0; int bi = i0;
        if (v1 < bv || (v1 == bv && i1 < bi)) { bv = v1; bi = i1; }
        part[(size_t)(n0 + t) * 8 + nb] = make_float2(bv, (float)(nb * 128 + bi));
    }
}

// ---------------------------------------------------------------------------
// vq_reduce: combine 8 partials per position; write indices; gather rows and
// write quantized as f4 (4 positions per thread, 4x4 register transpose).
// Fully overwrites the quantized region (which prep_z/vq_gemm used as scratch).
// grid: 256 x 256.
// ---------------------------------------------------------------------------
__global__ __launch_bounds__(256) void vq_reduce(const float2* __restrict__ part,
                                                 const float* __restrict__ e,
                                                 float* __restrict__ out_q,
                                                 float* __restrict__ out_i) {
    __shared__ int bidx[128];
    const int t  = threadIdx.x;
    const int p0 = blockIdx.x * 128;

    if (t < 128) {
        const int n = p0 + t;
        const float2* pr = part + (size_t)n * 8;
        float bv = pr[0].x; int bi = (int)pr[0].y;
        #pragma unroll
        for (int nb = 1; nb < 8; ++nb) {
            const float2 c = pr[nb];
            const int ci = (int)c.y;
            if (c.x < bv || (c.x == bv && ci < bi)) { bv = c.x; bi = ci; }
        }
        bidx[t] = bi;
        out_i[n] = (float)bi;
    }
    __syncthreads();

    const int pq = t & 31;               // position quad within block
    const int cs = t >> 5;               // channel set (8 x 64)
    const int n  = p0 + pq * 4;
    const int b  = n >> 10, hwp = n & 1023;

    const int r0 = bidx[pq * 4 + 0], r1 = bidx[pq * 4 + 1];
    const int r2 = bidx[pq * 4 + 2], r3 = bidx[pq * 4 + 3];
    const f4* e0 = (const f4*)(e + (size_t)r0 * CDIM) + cs * 16;
    const f4* e1 = (const f4*)(e + (size_t)r1 * CDIM) + cs * 16;
    const f4* e2 = (const f4*)(e + (size_t)r2 * CDIM) + cs * 16;
    const f4* e3 = (const f4*)(e + (size_t)r3 * CDIM) + cs * 16;
    float* oq = out_q + (size_t)b * CDIM * HW + hwp;

    #pragma unroll 4
    for (int q = 0; q < 16; ++q) {
        const f4 a = e0[q], bb = e1[q], c = e2[q], d = e3[q];
        const int cbase = cs * 64 + q * 4;
        *(f4*)(oq + (size_t)(cbase + 0) * HW) = f4{a.x, bb.x, c.x, d.x};
        *(f4*)(oq + (size_t)(cbase + 1) * HW) = f4{a.y, bb.y, c.y, d.y};
        *(f4*)(oq + (size_t)(cbase + 2) * HW) = f4{a.z, bb.z, c.z, d.z};
        *(f4*)(oq + (size_t)(cbase + 3) * HW) = f4{a.w, bb.w, c.w, d.w};
    }
}

// ---------------------------------------------------------------------------
extern "C" void kernel_launch(void* const* d_in, const int* in_sizes, int n_in,
                              void* d_out, int out_size, void* d_ws, size_t ws_size,
                              hipStream_t stream) {
    const float* z = (const float*)d_in[0];
    const float* e = (const float*)d_in[1];

    float* out_q = (float*)d_out;
    float* out_i = out_q + (out_size - NPOS);

    // z tile images live in the quantized-output region (64 MiB, dead until
    // vq_reduce fully overwrites it).
    unsigned short* Az = (unsigned short*)d_out;

    // ws (~4.2 MB): Bt 2MB | enorm 4KB | part 2MB
    unsigned short* Bt = (unsigned short*)d_ws;
    float*  enorm = (float*)((char*)d_ws + 2 * 1048576);
    float2* part  = (float2*)((char*)d_ws + 2 * 1048576 + 4096);

    prep_e<<<KDIM, 64, 0, stream>>>(e, Bt, enorm);
    prep_z<<<256, 256, 0, stream>>>(z, Az);
    vq_gemm<<<(NPOS / BM) * NNB, 256, 0, stream>>>(Az, Bt, enorm, part);
    vq_reduce<<<NPOS / 128, 256, 0, stream>>>(part, e, out_q, out_i);
}